// Round 6
// baseline (171.252 us; speedup 1.0000x reference)
//
#include <hip/hip_runtime.h>

// ---------------------------------------------------------------------------
// AttentionDecoder: B=64, S=512, H=1024, V=32000
// outputs (f32, concat): output [64,32000] | h_new [64,1024] | attn_w [64,512]
// ---------------------------------------------------------------------------

typedef __bf16 bf16;
typedef __attribute__((ext_vector_type(4))) float  f32x4;
typedef __attribute__((ext_vector_type(4))) float  fx4;
typedef __attribute__((ext_vector_type(8))) bf16   bf16x8;
typedef __attribute__((ext_vector_type(4))) bf16   bf16x4;
typedef __attribute__((ext_vector_type(4))) unsigned int u32x4;
typedef __attribute__((ext_vector_type(2))) unsigned int u32x2;

#define MFMA16x16x32(a, b, c) __builtin_amdgcn_mfma_f32_16x16x32_bf16(a, b, c, 0, 0, 0)

#define Bb   64
#define Ss   512
#define Hh   1024
#define Vv   32000
#define Mtot (Bb * Ss)          // 32768

// ---- d_ws layout (bytes) --------------------------------------------------
#define WS_HNEW_B    131072                  // 64*1024 bf16   = 128KB
#define WS_XC_B      262144                  // 64*2048 bf16   = 256KB
#define WS_W1A_B     524288                  // 1024*1024 bf16 = 2MB
#define WS_P_HB      2621440                 // [4][64][1024] f32 = 1MB
#define WS_P_HZ      3670016
#define WS_P_HN      4718592
#define WS_P_IZ      5767168
#define WS_P_IR      6815744
#define WS_P_IN      7864320
#define WS_SCORES    8912896                 // [16][32768] f32 = 2MB
#define WS_CTX       11010048                // [8][64][1024] f32 = 2MB
#define WS_ANNB      13107200                // 32768*1024 bf16 = 64MB
// total ~80.3MB

// ---- d_out offsets (floats) ----------------------------------------------
#define OUT_LOGITS   0
#define OUT_HNEW     2048000
#define OUT_AW       2113536

__device__ __forceinline__ float bf2f(unsigned short u) {
    unsigned int x = ((unsigned int)u) << 16;
    float f;
    __builtin_memcpy(&f, &x, 4);
    return f;
}

// async global->LDS, 16B per lane. LDS dest is wave-uniform base; HW writes
// base + lane*16.
__device__ __forceinline__ void gload_lds16(const bf16* g, bf16* l)
{
    __builtin_amdgcn_global_load_lds(
        (const __attribute__((address_space(1))) unsigned int*)g,
        (__attribute__((address_space(3))) unsigned int*)l,
        16, 0, 0);
}

// ===========================================================================
// k_pre: merged pre-attention work, role-split grid (3328 blocks x 256):
//  [0,192)    : M=64 GEMM  p_hB/p_hz/p_hn = h_prev(f32) @ {W1b,W_hz,W_hn}^T
//  [192,1280) : prep: embed gather -> xc_b[:,H:2H] ; W1a -> bf16
//  [1280,3328): convann: ann f32 -> annb bf16 (201MB stream, hides the rest)
// ===========================================================================
__global__ __launch_bounds__(256, 2) void k_pre(
    const int* __restrict__ x, const float* __restrict__ h_prev,
    const float* __restrict__ emb, const float* __restrict__ attn_W1,
    const float* __restrict__ W_hz, const float* __restrict__ W_hn,
    const float* __restrict__ ann,
    bf16* __restrict__ xc_b, bf16* __restrict__ W1a_b, bf16* __restrict__ annb,
    float* __restrict__ p_hB, float* __restrict__ p_hz, float* __restrict__ p_hn)
{
    __shared__ __align__(16) bf16 lA[2][64][72];
    __shared__ __align__(16) bf16 lB[2][64][72];

    int bid = blockIdx.x, t = threadIdx.x;

    if (bid >= 1280) {
        // ---- convann ----
        size_t i = ((size_t)(bid - 1280) * 256 + t) * 8;
        size_t stride = (size_t)2048 * 256 * 8;
        size_t n = (size_t)Mtot * Hh;
        for (; i < n; i += stride) {
            fx4 v0 = *(const fx4*)(ann + i);
            fx4 v1 = *(const fx4*)(ann + i + 4);
            bf16x8 o;
#pragma unroll
            for (int q = 0; q < 4; q++) { o[q] = (bf16)v0[q]; o[q + 4] = (bf16)v1[q]; }
            *(bf16x8*)(annb + i) = o;
        }
        return;
    }
    if (bid >= 192) {
        // ---- prep ----
        int sub = bid - 192;
        if (sub < 64) {
            int b = sub, row = x[b];
            for (int i = t; i < Hh; i += 256)
                xc_b[b * 2048 + Hh + i] = (bf16)emb[(size_t)row * Hh + i];
        } else {
            int row = sub - 64;
            int k4 = t * 4;
            fx4 v = *(const fx4*)(attn_W1 + (size_t)row * 2048 + k4);
            bf16x4 o;
#pragma unroll
            for (int q = 0; q < 4; q++) o[q] = (bf16)v[q];
            *(bf16x4*)(W1a_b + (size_t)row * Hh + k4) = o;
        }
        return;
    }

    // ---- M=64 GEMM role (f32 A = h_prev) ----
    int nb = bid & 15, sk = (bid >> 4) & 3, mat = bid >> 6;
    const float* Bp = (mat == 0) ? (attn_W1 + 1024) : (mat == 1 ? W_hz : W_hn);
    int ldb         = (mat == 0) ? 2048 : 1024;
    float* op       = (mat == 0) ? p_hB : (mat == 1 ? p_hz : p_hn);

    int n0 = nb * 64, k0 = sk * 256;
    int lane = t & 63, wid = t >> 6;
    int srow = t >> 2, schunk = t & 3;

    const float* agp = h_prev + (size_t)srow * 1024 + k0 + schunk * 16;
    const float* bgp = Bp + (size_t)(n0 + srow) * ldb + k0 + schunk * 16;

    f32x4 acc[4];
#pragma unroll
    for (int i = 0; i < 4; i++) acc[i] = (f32x4)0.0f;

    fx4 aRf[4], bRf[4];
#pragma unroll
    for (int q = 0; q < 4; q++) { aRf[q] = *(const fx4*)(agp + q * 4);
                                  bRf[q] = *(const fx4*)(bgp + q * 4); }
    {
        bf16x8 a0, a1, p0, p1;
#pragma unroll
        for (int q = 0; q < 4; q++) {
            a0[q] = (bf16)aRf[0][q]; a0[q + 4] = (bf16)aRf[1][q];
            a1[q] = (bf16)aRf[2][q]; a1[q + 4] = (bf16)aRf[3][q];
            p0[q] = (bf16)bRf[0][q]; p0[q + 4] = (bf16)bRf[1][q];
            p1[q] = (bf16)bRf[2][q]; p1[q + 4] = (bf16)bRf[3][q];
        }
        *(bf16x8*)&lA[0][srow][schunk * 16]     = a0;
        *(bf16x8*)&lA[0][srow][schunk * 16 + 8] = a1;
        *(bf16x8*)&lB[0][srow][schunk * 16]     = p0;
        *(bf16x8*)&lB[0][srow][schunk * 16 + 8] = p1;
    }
    __syncthreads();

    int cur = 0;
    for (int ks = 0; ks < 4; ks++) {
        if (ks + 1 < 4) {
#pragma unroll
            for (int q = 0; q < 4; q++) {
                aRf[q] = *(const fx4*)(agp + (ks + 1) * 64 + q * 4);
                bRf[q] = *(const fx4*)(bgp + (ks + 1) * 64 + q * 4);
            }
        }
        int rA = lane & 15;
        int kc = (lane >> 4) * 8;
#pragma unroll
        for (int kk = 0; kk < 2; kk++) {
            bf16x8 bfr = *(bf16x8*)&lB[cur][wid * 16 + rA][kk * 32 + kc];
#pragma unroll
            for (int i = 0; i < 4; i++) {
                bf16x8 af = *(bf16x8*)&lA[cur][i * 16 + rA][kk * 32 + kc];
                acc[i] = MFMA16x16x32(af, bfr, acc[i]);
            }
        }
        if (ks + 1 < 4) {
            int nxt = cur ^ 1;
            bf16x8 a0, a1, p0, p1;
#pragma unroll
            for (int q = 0; q < 4; q++) {
                a0[q] = (bf16)aRf[0][q]; a0[q + 4] = (bf16)aRf[1][q];
                a1[q] = (bf16)aRf[2][q]; a1[q + 4] = (bf16)aRf[3][q];
                p0[q] = (bf16)bRf[0][q]; p0[q + 4] = (bf16)bRf[1][q];
                p1[q] = (bf16)bRf[2][q]; p1[q + 4] = (bf16)bRf[3][q];
            }
            *(bf16x8*)&lA[nxt][srow][schunk * 16]     = a0;
            *(bf16x8*)&lA[nxt][srow][schunk * 16 + 8] = a1;
            *(bf16x8*)&lB[nxt][srow][schunk * 16]     = p0;
            *(bf16x8*)&lB[nxt][srow][schunk * 16 + 8] = p1;
        }
        __syncthreads();
        cur ^= 1;
    }

    int n = n0 + wid * 16 + (lane & 15);
#pragma unroll
    for (int i = 0; i < 4; i++)
#pragma unroll
        for (int r = 0; r < 4; r++) {
            int m = i * 16 + (lane >> 4) * 4 + r;
            op[(size_t)(sk * 64 + m) * 1024 + n] = acc[i][r];
        }
}

// ===========================================================================
// k_sgemm: M=64 GEMM, out[m][n] = sum_k A_bf16[m][k] * (f32)Bmat[n][k]
// tile BM=64 BN=64 BK=64, 4 waves, dbuf reg-staged. (gates + W_out)
// ===========================================================================
__global__ __launch_bounds__(256, 2) void k_sgemm(
    const bf16* __restrict__ A, int lda, int kchunk,
    const float* __restrict__ B0, const float* __restrict__ B1, const float* __restrict__ B2,
    int ldb0, int ldb1, int ldb2,
    float* __restrict__ o0, float* __restrict__ o1, float* __restrict__ o2,
    const float* __restrict__ bias, int N, int finalOut)
{
    __shared__ __align__(16) bf16 lA[2][64][72];
    __shared__ __align__(16) bf16 lB[2][64][72];

    int nb = blockIdx.x, sk = blockIdx.y, mat = blockIdx.z;
    const float* Bp = (mat == 0) ? B0 : (mat == 1 ? B1 : B2);
    int ldb         = (mat == 0) ? ldb0 : (mat == 1 ? ldb1 : ldb2);
    float* op       = (mat == 0) ? o0 : (mat == 1 ? o1 : o2);

    int n0 = nb * 64, k0 = sk * kchunk;
    int t = threadIdx.x, lane = t & 63, wid = t >> 6;
    int srow = t >> 2, schunk = t & 3;

    const bf16*  agp = A  + (size_t)srow * lda + k0 + schunk * 16;
    const float* bgp = Bp + (size_t)(n0 + srow) * ldb + k0 + schunk * 16;

    f32x4 acc[4];
#pragma unroll
    for (int i = 0; i < 4; i++) acc[i] = (f32x4)0.0f;

    u32x4 aR0, aR1; fx4 bRf[4];
    int nk = kchunk >> 6;

    aR0 = *(const u32x4*)(agp);
    aR1 = *(const u32x4*)(agp + 8);
#pragma unroll
    for (int q = 0; q < 4; q++) bRf[q] = *(const fx4*)(bgp + q * 4);
    {
        *(u32x4*)&lA[0][srow][schunk * 16]     = aR0;
        *(u32x4*)&lA[0][srow][schunk * 16 + 8] = aR1;
        bf16x8 p0, p1;
#pragma unroll
        for (int q = 0; q < 4; q++) {
            p0[q] = (bf16)bRf[0][q]; p0[q + 4] = (bf16)bRf[1][q];
            p1[q] = (bf16)bRf[2][q]; p1[q + 4] = (bf16)bRf[3][q];
        }
        *(bf16x8*)&lB[0][srow][schunk * 16]     = p0;
        *(bf16x8*)&lB[0][srow][schunk * 16 + 8] = p1;
    }
    __syncthreads();

    int cur = 0;
    for (int ks = 0; ks < nk; ks++) {
        if (ks + 1 < nk) {
            aR0 = *(const u32x4*)(agp + (ks + 1) * 64);
            aR1 = *(const u32x4*)(agp + (ks + 1) * 64 + 8);
#pragma unroll
            for (int q = 0; q < 4; q++) bRf[q] = *(const fx4*)(bgp + (ks + 1) * 64 + q * 4);
        }
        int rA = lane & 15;
        int kc = (lane >> 4) * 8;
#pragma unroll
        for (int kk = 0; kk < 2; kk++) {
            bf16x8 bfr = *(bf16x8*)&lB[cur][wid * 16 + rA][kk * 32 + kc];
#pragma unroll
            for (int i = 0; i < 4; i++) {
                bf16x8 af = *(bf16x8*)&lA[cur][i * 16 + rA][kk * 32 + kc];
                acc[i] = MFMA16x16x32(af, bfr, acc[i]);
            }
        }
        if (ks + 1 < nk) {
            int nxt = cur ^ 1;
            *(u32x4*)&lA[nxt][srow][schunk * 16]     = aR0;
            *(u32x4*)&lA[nxt][srow][schunk * 16 + 8] = aR1;
            bf16x8 p0, p1;
#pragma unroll
            for (int q = 0; q < 4; q++) {
                p0[q] = (bf16)bRf[0][q]; p0[q + 4] = (bf16)bRf[1][q];
                p1[q] = (bf16)bRf[2][q]; p1[q + 4] = (bf16)bRf[3][q];
            }
            *(bf16x8*)&lB[nxt][srow][schunk * 16]     = p0;
            *(bf16x8*)&lB[nxt][srow][schunk * 16 + 8] = p1;
        }
        __syncthreads();
        cur ^= 1;
    }

    int n = n0 + wid * 16 + (lane & 15);
#pragma unroll
    for (int i = 0; i < 4; i++) {
#pragma unroll
        for (int r = 0; r < 4; r++) {
            int m = i * 16 + (lane >> 4) * 4 + r;
            float v = acc[i][r];
            if (finalOut) op[(size_t)m * N + n] = v + bias[n];
            else          op[(size_t)(sk * 64 + m) * N + n] = v;
        }
    }
}

// ===========================================================================
// k_attn v6: 256x256, BK=64, 8 waves, m201-style quadrant 4-phase/K-tile.
// LDS 128KB: [buf2][A 32KB | B 32KB], halves = rows 0-127 / 128-255, 128B
// rows, 16B-chunk XOR swizzle c ^= (row&7) (both sides, R3-verified).
// Phase = {ds-read quadrant frags, issue staging half, s_barrier,
//          setprio(1), 16 MFMA, setprio(0), counted vmcnt, s_barrier}.
// Stage order per tile t (-> buf nxt, for t+1): P0: Ah0+Bh0 (4 calls),
// P1: Ah1 (2), P3: Bh1 (2).  Waits: P0-end vmcnt(6), P1-end vmcnt(6),
// P3-end vmcnt(4); tail tile: 2 -> 0. Never drains in steady state.
// Quadrants: P0=(i0,j0) P1=(i1,j0) P2=(i1,j1) P3=(i0,j1); A reused P1->P2,
// B reused P0->P1 and P2->P3.
// Fused epilogue: relu(hA+hB+b1)*W2 -> scores_part[nbp*4+wn][m].
// ===========================================================================
__global__ __launch_bounds__(512, 2) void k_attn(
    const bf16* __restrict__ annb, const bf16* __restrict__ Bw,
    const float* __restrict__ p_hB, const float* __restrict__ b1,
    const float* __restrict__ W2, float* __restrict__ scores_part)
{
    extern __shared__ char smem[];

    int bid = blockIdx.x;
    int wgid = (bid & 7) * 64 + (bid >> 3);       // XCD-contiguous (512%8==0)
    int mb = wgid >> 2, nbp = wgid & 3;

    int t = threadIdx.x, lane = t & 63, wid = t >> 6;
    int wm = wid >> 2, wn = wid & 3;
    int r = lane & 15, q = lane >> 4;

    // staging lane constants (linear LDS dest, inverse-swizzled source)
    int srow = t >> 3;                            // 0..63
    int gc   = (t & 7) ^ (srow & 7);
    size_t goff = (size_t)srow * 1024 + gc * 8;
    int doff = wid * 1024;
    const bf16* aSrc = annb + (size_t)mb * 262144;
    const bf16* bSrc = Bw   + (size_t)nbp * 262144;

    // ds_read lane constants
    int e0 = (q ^ (r & 7)) * 16, e1 = e0 ^ 64;    // swizzled chunk bytes
    int rowAoff = (wm * 64 + r) * 128;            // + ip*2048 + IH*16384
    int rowBoff = 32768 + (wn * 32 + r) * 128;    // + jp*2048 + JH*16384

#define STAGEOP(src, half, buf, mat, kt) do {                                  \
        const bf16* s_ = (src) + (half) * 131072 + (size_t)(kt) * 64 + goff;   \
        char* d_ = smem + (buf) * 65536 + (mat) * 32768 + (half) * 16384 + doff; \
        gload_lds16(s_, (bf16*)d_);                                            \
        gload_lds16(s_ + 65536, (bf16*)(d_ + 8192));                           \
    } while (0)

#define VMW(n) asm volatile("s_waitcnt vmcnt(" #n ")" ::: "memory")

    f32x4 acc[8][4];
#pragma unroll
    for (int i = 0; i < 8; i++)
#pragma unroll
        for (int j = 0; j < 4; j++) acc[i][j] = (f32x4)0.0f;

    bf16x8 aq[4][2], bq[2][2];   // frag regs reused across adjacent phases

#define PHASE(IH, JH, RA, RB, STG, WAITQ) do {                                 \
        if (RA) {                                                              \
            _Pragma("unroll")                                                  \
            for (int ip = 0; ip < 4; ip++) {                                   \
                const char* pa_ = smem + cur * 65536 + (IH) * 16384            \
                                + rowAoff + ip * 2048;                         \
                aq[ip][0] = *(const bf16x8*)(pa_ + e0);                        \
                aq[ip][1] = *(const bf16x8*)(pa_ + e1);                        \
            }                                                                  \
        }                                                                      \
        if (RB) {                                                              \
            _Pragma("unroll")                                                  \
            for (int jp = 0; jp < 2; jp++) {                                   \
                const char* pb_ = smem + cur * 65536 + (JH) * 16384            \
                                + rowBoff + jp * 2048;                         \
                bq[jp][0] = *(const bf16x8*)(pb_ + e0);                        \
                bq[jp][1] = *(const bf16x8*)(pb_ + e1);                        \
            }                                                                  \
        }                                                                      \
        STG;                                                                   \
        __builtin_amdgcn_s_barrier();                                          \
        __builtin_amdgcn_s_setprio(1);                                         \
        _Pragma("unroll")                                                      \
        for (int ip = 0; ip < 4; ip++)                                         \
            _Pragma("unroll")                                                  \
            for (int jp = 0; jp < 2; jp++)                                     \
                _Pragma("unroll")                                              \
                for (int ks = 0; ks < 2; ks++)                                 \
                    acc[(IH) * 4 + ip][(JH) * 2 + jp] =                        \
                        MFMA16x16x32(aq[ip][ks], bq[jp][ks],                   \
                                     acc[(IH) * 4 + ip][(JH) * 2 + jp]);       \
        __builtin_amdgcn_s_setprio(0);                                         \
        WAITQ;                                                                 \
        __builtin_amdgcn_s_barrier();                                          \
    } while (0)

    // prologue: tile 0 fully staged (8 calls), drained
    STAGEOP(aSrc, 0, 0, 0, 0);
    STAGEOP(bSrc, 0, 0, 1, 0);
    STAGEOP(aSrc, 1, 0, 0, 0);
    STAGEOP(bSrc, 1, 0, 1, 0);
    VMW(0);
    __builtin_amdgcn_s_barrier();

#pragma unroll 1
    for (int kt = 0; kt < 15; kt++) {
        int cur = kt & 1, nxt = cur ^ 1;
        PHASE(0, 0, 1, 1, { STAGEOP(aSrc, 0, nxt, 0, kt + 1);
                            STAGEOP(bSrc, 0, nxt, 1, kt + 1); }, VMW(6));
        PHASE(1, 0, 1, 0, { STAGEOP(aSrc, 1, nxt, 0, kt + 1); }, VMW(6));
        PHASE(1, 1, 0, 1, , (void)0);
        PHASE(0, 1, 1, 0, { STAGEOP(bSrc, 1, nxt, 1, kt + 1); }, VMW(4));
    }
    {   // tail kt = 15 (cur = 1): no staging; drain remaining counted
        int cur = 1;
        PHASE(0, 0, 1, 1, , VMW(2));
        PHASE(1, 0, 1, 0, , VMW(0));
        PHASE(1, 1, 0, 1, , (void)0);
        PHASE(0, 1, 1, 0, , (void)0);
    }
#undef PHASE
#undef STAGEOP

    // fused epilogue: relu(hA + hB + b1) * W2, reduce over this block's n
    int m0 = mb * 256, n0g = nbp * 256;
    int b = m0 >> 9;                               // single batch per block
    float hb[4], w2v[4];
#pragma unroll
    for (int j = 0; j < 4; j++) {
        int n = n0g + (j >> 1) * 128 + wn * 32 + (j & 1) * 16 + r;
        float h = p_hB[b * Hh + n] + p_hB[65536 + b * Hh + n]
                + p_hB[131072 + b * Hh + n] + p_hB[196608 + b * Hh + n];
        hb[j]  = h + b1[n];
        w2v[j] = W2[n];
    }
    float red[32];
#pragma unroll
    for (int i = 0; i < 8; i++)
#pragma unroll
        for (int rr = 0; rr < 4; rr++) {
            float s = 0.f;
#pragma unroll
            for (int j = 0; j < 4; j++) {
                float v = acc[i][j][rr] + hb[j];
                v = fmaxf(v, 0.f);
                s += v * w2v[j];
            }
            red[i * 4 + rr] = s;
        }
#pragma unroll
    for (int mask = 1; mask <= 8; mask <<= 1)
#pragma unroll
        for (int p = 0; p < 32; p++)
            red[p] += __shfl_xor(red[p], mask, 64);

    if (r == 0) {
        float* sp = scores_part + (size_t)(nbp * 4 + wn) * Mtot;
#pragma unroll
        for (int i = 0; i < 8; i++) {
            int m = m0 + wm * 64 + (i & 3) * 16 + (i >> 2) * 128 + q * 4;
#pragma unroll
            for (int rr = 0; rr < 4; rr++)
                sp[m + rr] = red[i * 4 + rr];
        }
    }
}

// ===========================================================================
// k_softmax: per b (64 blocks x 512 thr): sum 16 partials, softmax over s.
// ===========================================================================
__global__ void k_softmax(const float* __restrict__ scores_part, float* __restrict__ aw)
{
    int b = blockIdx.x, s = threadIdx.x;
    int lane = s & 63, wid = s >> 6;
    float v = 0.f;
#pragma unroll
    for (int p = 0; p < 16; p++) v += scores_part[(size_t)p * Mtot + b * Ss + s];

    __shared__ float redm[8], redsum[8];
    float m = v;
#pragma unroll
    for (int mask = 32; mask; mask >>= 1) m = fmaxf(m, __shfl_xor(m, mask, 64));
    if (lane == 0) redm[wid] = m;
    __syncthreads();
    float bm = redm[0];
#pragma unroll
    for (int w = 1; w < 8; w++) bm = fmaxf(bm, redm[w]);

    float e = expf(v - bm);
    float ss = e;
#pragma unroll
    for (int mask = 32; mask; mask >>= 1) ss += __shfl_xor(ss, mask, 64);
    if (lane == 0) redsum[wid] = ss;
    __syncthreads();
    float tot = 0.f;
#pragma unroll
    for (int w = 0; w < 8; w++) tot += redsum[w];

    aw[b * Ss + s] = e / tot;
}

// ===========================================================================
// k_context: ctx_part[sc][b][h] = sum_{s in 64-chunk} aw[b,s]*annb[b,s,h]
// ===========================================================================
__global__ void k_context(const bf16* __restrict__ annb, const float* __restrict__ aw,
                          float* __restrict__ ctx_part)
{
    __shared__ float law[64];
    int bid = blockIdx.x;
    int b = bid >> 3, sc = bid & 7;
    int t = threadIdx.x;
    if (t < 64) law[t] = aw[b * Ss + sc * 64 + t];
    __syncthreads();
    int h0 = t * 4;
    const bf16* ap = annb + (size_t)(b * Ss + sc * 64) * Hh + h0;
    float a0 = 0, a1 = 0, a2 = 0, a3 = 0;
#pragma unroll 4
    for (int s2 = 0; s2 < 64; s2++) {
        float w = law[s2];
        u32x2 v = *(const u32x2*)(ap + (size_t)s2 * Hh);
        a0 += w * bf2f((unsigned short)(v[0] & 0xffff));
        a1 += w * bf2f((unsigned short)(v[0] >> 16));
        a2 += w * bf2f((unsigned short)(v[1] & 0xffff));
        a3 += w * bf2f((unsigned short)(v[1] >> 16));
    }
    fx4 o; o[0] = a0; o[1] = a1; o[2] = a2; o[3] = a3;
    *(fx4*)(ctx_part + sc * 65536 + b * Hh + h0) = o;
}

// ===========================================================================
// k_xc: xc_b[:, 0:H] = bf16(sum of 8 ctx partials)
// ===========================================================================
__global__ void k_xc(const float* __restrict__ ctx_part, bf16* __restrict__ xc_b)
{
    int idx = blockIdx.x * 256 + threadIdx.x;          // 65536
    float c = 0.f;
#pragma unroll
    for (int p = 0; p < 8; p++) c += ctx_part[p * 65536 + idx];
    int b = idx >> 10, h = idx & 1023;
    xc_b[b * 2048 + h] = (bf16)c;
}

// ===========================================================================
// k_gru: gates + h_new (reads 4-way split-K partials)
// ===========================================================================
__global__ void k_gru(const float* __restrict__ p_iz, const float* __restrict__ p_ir,
                      const float* __restrict__ p_in, const float* __restrict__ p_hz,
                      const float* __restrict__ p_hn,
                      const float* __restrict__ b_iz, const float* __restrict__ b_ir,
                      const float* __restrict__ b_in, const float* __restrict__ b_hz,
                      const float* __restrict__ b_hn,
                      const float* __restrict__ h_prev,
                      float* __restrict__ out_h, bf16* __restrict__ h_new_b)
{
    int idx = blockIdx.x * 256 + threadIdx.x;          // 65536
    int o = idx & 1023;
    float iz = p_iz[idx] + p_iz[65536 + idx] + p_iz[131072 + idx] + p_iz[196608 + idx];
    float ir = p_ir[idx] + p_ir[65536 + idx] + p_ir[131072 + idx] + p_ir[196608 + idx];
    float in_ = p_in[idx] + p_in[65536 + idx] + p_in[131072 + idx] + p_in[196608 + idx];
    float hz = p_hz[idx] + p_hz[65536 + idx] + p_hz[131072 + idx] + p_hz[196608 + idx];
    float hn = p_hn[idx] + p_hn[65536 + idx] + p_hn[131072 + idx] + p_hn[196608 + idx];
    hz += b_hz[o];
    hn += b_hn[o];
    float z = 1.f / (1.f + expf(-(iz + b_iz[o] + hz)));
    float r = 1.f / (1.f + expf(-(ir + b_ir[o] + hz)));
    float g = tanhf(in_ + b_in[o] + r * hn);
    float hp = h_prev[idx];
    float hnew = (1.f - z) * g + z * hp;
    out_h[idx] = hnew;
    h_new_b[idx] = (bf16)hnew;
}

// ===========================================================================
extern "C" void kernel_launch(void* const* d_in, const int* in_sizes, int n_in,
                              void* d_out, int out_size, void* d_ws, size_t ws_size,
                              hipStream_t stream)
{
    const int*   x        = (const int*)d_in[0];
    const float* h_prev   = (const float*)d_in[1];
    const float* ann      = (const float*)d_in[2];
    const float* emb      = (const float*)d_in[3];
    const float* attn_W1  = (const float*)d_in[4];
    const float* attn_b1  = (const float*)d_in[5];
    const float* attn_W2  = (const float*)d_in[6];
    const float* W_ir     = (const float*)d_in[8];
    const float* b_ir     = (const float*)d_in[9];
    const float* W_iz     = (const float*)d_in[10];
    const float* b_iz     = (const float*)d_in[11];
    const float* W_in     = (const float*)d_in[12];
    const float* b_in     = (const float*)d_in[13];
    const float* W_hz     = (const float*)d_in[14];
    const float* b_hz     = (const float*)d_in[15];
    const float* W_hn     = (const float*)d_in[16];
    const float* b_hn     = (const float*)d_in[17];
    const float* W_out    = (const float*)d_in[18];
    const float* b_out    = (const float*)d_in[19];

    float* out = (float*)d_out;
    char*  ws  = (char*)d_ws;

    bf16*  h_new_b  = (bf16*)(ws + WS_HNEW_B);
    bf16*  xc_b     = (bf16*)(ws + WS_XC_B);
    bf16*  W1a_b    = (bf16*)(ws + WS_W1A_B);
    float* p_hB     = (float*)(ws + WS_P_HB);
    float* p_hz     = (float*)(ws + WS_P_HZ);
    float* p_hn     = (float*)(ws + WS_P_HN);
    float* p_iz     = (float*)(ws + WS_P_IZ);
    float* p_ir     = (float*)(ws + WS_P_IR);
    float* p_in     = (float*)(ws + WS_P_IN);
    float* scores_p = (float*)(ws + WS_SCORES);
    float* ctx_part = (float*)(ws + WS_CTX);
    bf16*  annb     = (bf16*)(ws + WS_ANNB);

    // allow 128KB dynamic LDS for k_attn (host-side attribute, capture-safe)
    hipFuncSetAttribute(reinterpret_cast<const void*>(k_attn),
                        hipFuncAttributeMaxDynamicSharedMemorySize, 131072);

    // 1) merged pre-work: convann + prep + hB/hz/hn GEMMs (overlapped)
    k_pre<<<3328, 256, 0, stream>>>(x, h_prev, emb, attn_W1, W_hz, W_hn, ann,
                                    xc_b, W1a_b, annb, p_hB, p_hz, p_hn);

    // 2) fused attention GEMM -> 16 score partials
    k_attn<<<512, 512, 131072, stream>>>(annb, W1a_b, p_hB, attn_b1, attn_W2,
                                         scores_p);

    // 3) softmax -> attention weights (final output region)
    k_softmax<<<64, 512, 0, stream>>>(scores_p, out + OUT_AW);

    // 4) context = sum_s aw * annb  (8 s-chunks)
    k_context<<<512, 256, 0, stream>>>(annb, out + OUT_AW, ctx_part);

    // 5) xc = [context, embed] in bf16
    k_xc<<<256, 256, 0, stream>>>(ctx_part, xc_b);

    // 6) gate GEMMs (xc @ {W_iz, W_ir, W_in}^T), K=2048, split-K=4
    {
        dim3 g(16, 4, 3);
        k_sgemm<<<g, 256, 0, stream>>>(xc_b, 2048, 512,
                                       W_iz, W_ir, W_in, 2048, 2048, 2048,
                                       p_iz, p_ir, p_in, nullptr, 1024, 0);
    }

    // 7) GRU elementwise -> h_new (f32 out + bf16 ws)
    k_gru<<<256, 256, 0, stream>>>(p_iz, p_ir, p_in, p_hz, p_hn,
                                   b_iz, b_ir, b_in, b_hz, b_hn,
                                   h_prev, out + OUT_HNEW, h_new_b);

    // 8) output logits = h_new @ W_out^T + b_out
    {
        dim3 g(500, 1, 1);
        k_sgemm<<<g, 256, 0, stream>>>(h_new_b, 1024, 1024,
                                       W_out, W_out, W_out, 1024, 1024, 1024,
                                       out + OUT_LOGITS, nullptr, nullptr,
                                       b_out, 32000, 1);
    }
}

// Round 8
// 170.518 us; speedup vs baseline: 1.0043x; 1.0043x over previous
//
#include <hip/hip_runtime.h>

// ---------------------------------------------------------------------------
// AttentionDecoder: B=64, S=512, H=1024, V=32000
// outputs (f32, concat): output [64,32000] | h_new [64,1024] | attn_w [64,512]
// ---------------------------------------------------------------------------

typedef __bf16 bf16;
typedef __attribute__((ext_vector_type(4))) float  f32x4;
typedef __attribute__((ext_vector_type(4))) float  fx4;
typedef __attribute__((ext_vector_type(8))) bf16   bf16x8;
typedef __attribute__((ext_vector_type(4))) bf16   bf16x4;
typedef __attribute__((ext_vector_type(4))) unsigned int u32x4;
typedef __attribute__((ext_vector_type(2))) unsigned int u32x2;

#define MFMA16x16x32(a, b, c) __builtin_amdgcn_mfma_f32_16x16x32_bf16(a, b, c, 0, 0, 0)

#define Bb   64
#define Ss   512
#define Hh   1024
#define Vv   32000
#define Mtot (Bb * Ss)          // 32768

// ---- d_ws layout (bytes) --------------------------------------------------
#define WS_HNEW_B    131072                  // 64*1024 bf16   = 128KB
#define WS_XC_B      262144                  // 64*2048 bf16   = 256KB
#define WS_W1A_B     524288                  // 1024*1024 bf16 = 2MB
#define WS_P_HB      2621440                 // [4][64][1024] f32 = 1MB
#define WS_P_HZ      3670016
#define WS_P_HN      4718592
#define WS_P_IZ      5767168
#define WS_P_IR      6815744
#define WS_P_IN      7864320
#define WS_SCORES    8912896                 // [16][32768] f32 = 2MB
#define WS_CTX       11010048                // [8][64][1024] f32 = 2MB
#define WS_ANNB      13107200                // 32768*1024 bf16 = 64MB
// total ~80.3MB

// ---- d_out offsets (floats) ----------------------------------------------
#define OUT_LOGITS   0
#define OUT_HNEW     2048000
#define OUT_AW       2113536

__device__ __forceinline__ float bf2f(unsigned short u) {
    unsigned int x = ((unsigned int)u) << 16;
    float f;
    __builtin_memcpy(&f, &x, 4);
    return f;
}

// async global->LDS, 16B per lane. LDS dest is wave-uniform base; HW writes
// base + lane*16.
__device__ __forceinline__ void gload_lds16(const bf16* g, bf16* l)
{
    __builtin_amdgcn_global_load_lds(
        (const __attribute__((address_space(1))) unsigned int*)g,
        (__attribute__((address_space(3))) unsigned int*)l,
        16, 0, 0);
}

// ===========================================================================
// k_pre: merged pre-attention work, role-split grid (3328 blocks x 256):
//  [0,192)    : M=64 GEMM  p_hB/p_hz/p_hn = h_prev(f32) @ {W1b,W_hz,W_hn}^T
//  [192,1280) : prep: embed gather -> xc_b[:,H:2H] ; W1a -> bf16
//  [1280,3328): convann: ann f32 -> annb bf16 (201MB stream, hides the rest)
// ===========================================================================
__global__ __launch_bounds__(256, 2) void k_pre(
    const int* __restrict__ x, const float* __restrict__ h_prev,
    const float* __restrict__ emb, const float* __restrict__ attn_W1,
    const float* __restrict__ W_hz, const float* __restrict__ W_hn,
    const float* __restrict__ ann,
    bf16* __restrict__ xc_b, bf16* __restrict__ W1a_b, bf16* __restrict__ annb,
    float* __restrict__ p_hB, float* __restrict__ p_hz, float* __restrict__ p_hn)
{
    __shared__ __align__(16) bf16 lA[2][64][72];
    __shared__ __align__(16) bf16 lB[2][64][72];

    int bid = blockIdx.x, t = threadIdx.x;

    if (bid >= 1280) {
        // ---- convann ----
        size_t i = ((size_t)(bid - 1280) * 256 + t) * 8;
        size_t stride = (size_t)2048 * 256 * 8;
        size_t n = (size_t)Mtot * Hh;
        for (; i < n; i += stride) {
            fx4 v0 = *(const fx4*)(ann + i);
            fx4 v1 = *(const fx4*)(ann + i + 4);
            bf16x8 o;
#pragma unroll
            for (int q = 0; q < 4; q++) { o[q] = (bf16)v0[q]; o[q + 4] = (bf16)v1[q]; }
            *(bf16x8*)(annb + i) = o;
        }
        return;
    }
    if (bid >= 192) {
        // ---- prep ----
        int sub = bid - 192;
        if (sub < 64) {
            int b = sub, row = x[b];
            for (int i = t; i < Hh; i += 256)
                xc_b[b * 2048 + Hh + i] = (bf16)emb[(size_t)row * Hh + i];
        } else {
            int row = sub - 64;
            int k4 = t * 4;
            fx4 v = *(const fx4*)(attn_W1 + (size_t)row * 2048 + k4);
            bf16x4 o;
#pragma unroll
            for (int q = 0; q < 4; q++) o[q] = (bf16)v[q];
            *(bf16x4*)(W1a_b + (size_t)row * Hh + k4) = o;
        }
        return;
    }

    // ---- M=64 GEMM role (f32 A = h_prev) ----
    int nb = bid & 15, sk = (bid >> 4) & 3, mat = bid >> 6;
    const float* Bp = (mat == 0) ? (attn_W1 + 1024) : (mat == 1 ? W_hz : W_hn);
    int ldb         = (mat == 0) ? 2048 : 1024;
    float* op       = (mat == 0) ? p_hB : (mat == 1 ? p_hz : p_hn);

    int n0 = nb * 64, k0 = sk * 256;
    int lane = t & 63, wid = t >> 6;
    int srow = t >> 2, schunk = t & 3;

    const float* agp = h_prev + (size_t)srow * 1024 + k0 + schunk * 16;
    const float* bgp = Bp + (size_t)(n0 + srow) * ldb + k0 + schunk * 16;

    f32x4 acc[4];
#pragma unroll
    for (int i = 0; i < 4; i++) acc[i] = (f32x4)0.0f;

    fx4 aRf[4], bRf[4];
#pragma unroll
    for (int q = 0; q < 4; q++) { aRf[q] = *(const fx4*)(agp + q * 4);
                                  bRf[q] = *(const fx4*)(bgp + q * 4); }
    {
        bf16x8 a0, a1, p0, p1;
#pragma unroll
        for (int q = 0; q < 4; q++) {
            a0[q] = (bf16)aRf[0][q]; a0[q + 4] = (bf16)aRf[1][q];
            a1[q] = (bf16)aRf[2][q]; a1[q + 4] = (bf16)aRf[3][q];
            p0[q] = (bf16)bRf[0][q]; p0[q + 4] = (bf16)bRf[1][q];
            p1[q] = (bf16)bRf[2][q]; p1[q + 4] = (bf16)bRf[3][q];
        }
        *(bf16x8*)&lA[0][srow][schunk * 16]     = a0;
        *(bf16x8*)&lA[0][srow][schunk * 16 + 8] = a1;
        *(bf16x8*)&lB[0][srow][schunk * 16]     = p0;
        *(bf16x8*)&lB[0][srow][schunk * 16 + 8] = p1;
    }
    __syncthreads();

    int cur = 0;
    for (int ks = 0; ks < 4; ks++) {
        if (ks + 1 < 4) {
#pragma unroll
            for (int q = 0; q < 4; q++) {
                aRf[q] = *(const fx4*)(agp + (ks + 1) * 64 + q * 4);
                bRf[q] = *(const fx4*)(bgp + (ks + 1) * 64 + q * 4);
            }
        }
        int rA = lane & 15;
        int kc = (lane >> 4) * 8;
#pragma unroll
        for (int kk = 0; kk < 2; kk++) {
            bf16x8 bfr = *(bf16x8*)&lB[cur][wid * 16 + rA][kk * 32 + kc];
#pragma unroll
            for (int i = 0; i < 4; i++) {
                bf16x8 af = *(bf16x8*)&lA[cur][i * 16 + rA][kk * 32 + kc];
                acc[i] = MFMA16x16x32(af, bfr, acc[i]);
            }
        }
        if (ks + 1 < 4) {
            int nxt = cur ^ 1;
            bf16x8 a0, a1, p0, p1;
#pragma unroll
            for (int q = 0; q < 4; q++) {
                a0[q] = (bf16)aRf[0][q]; a0[q + 4] = (bf16)aRf[1][q];
                a1[q] = (bf16)aRf[2][q]; a1[q + 4] = (bf16)aRf[3][q];
                p0[q] = (bf16)bRf[0][q]; p0[q + 4] = (bf16)bRf[1][q];
                p1[q] = (bf16)bRf[2][q]; p1[q + 4] = (bf16)bRf[3][q];
            }
            *(bf16x8*)&lA[nxt][srow][schunk * 16]     = a0;
            *(bf16x8*)&lA[nxt][srow][schunk * 16 + 8] = a1;
            *(bf16x8*)&lB[nxt][srow][schunk * 16]     = p0;
            *(bf16x8*)&lB[nxt][srow][schunk * 16 + 8] = p1;
        }
        __syncthreads();
        cur ^= 1;
    }

    int n = n0 + wid * 16 + (lane & 15);
#pragma unroll
    for (int i = 0; i < 4; i++)
#pragma unroll
        for (int r = 0; r < 4; r++) {
            int m = i * 16 + (lane >> 4) * 4 + r;
            op[(size_t)(sk * 64 + m) * 1024 + n] = acc[i][r];
        }
}

// ===========================================================================
// k_sgemm: M=64 GEMM, out[m][n] = sum_k A_bf16[m][k] * (f32)Bmat[n][k]
// tile BM=64 BN=64 BK=64, 4 waves, dbuf reg-staged. (gates + W_out)
// ===========================================================================
__global__ __launch_bounds__(256, 2) void k_sgemm(
    const bf16* __restrict__ A, int lda, int kchunk,
    const float* __restrict__ B0, const float* __restrict__ B1, const float* __restrict__ B2,
    int ldb0, int ldb1, int ldb2,
    float* __restrict__ o0, float* __restrict__ o1, float* __restrict__ o2,
    const float* __restrict__ bias, int N, int finalOut)
{
    __shared__ __align__(16) bf16 lA[2][64][72];
    __shared__ __align__(16) bf16 lB[2][64][72];

    int nb = blockIdx.x, sk = blockIdx.y, mat = blockIdx.z;
    const float* Bp = (mat == 0) ? B0 : (mat == 1 ? B1 : B2);
    int ldb         = (mat == 0) ? ldb0 : (mat == 1 ? ldb1 : ldb2);
    float* op       = (mat == 0) ? o0 : (mat == 1 ? o1 : o2);

    int n0 = nb * 64, k0 = sk * kchunk;
    int t = threadIdx.x, lane = t & 63, wid = t >> 6;
    int srow = t >> 2, schunk = t & 3;

    const bf16*  agp = A  + (size_t)srow * lda + k0 + schunk * 16;
    const float* bgp = Bp + (size_t)(n0 + srow) * ldb + k0 + schunk * 16;

    f32x4 acc[4];
#pragma unroll
    for (int i = 0; i < 4; i++) acc[i] = (f32x4)0.0f;

    u32x4 aR0, aR1; fx4 bRf[4];
    int nk = kchunk >> 6;

    aR0 = *(const u32x4*)(agp);
    aR1 = *(const u32x4*)(agp + 8);
#pragma unroll
    for (int q = 0; q < 4; q++) bRf[q] = *(const fx4*)(bgp + q * 4);
    {
        *(u32x4*)&lA[0][srow][schunk * 16]     = aR0;
        *(u32x4*)&lA[0][srow][schunk * 16 + 8] = aR1;
        bf16x8 p0, p1;
#pragma unroll
        for (int q = 0; q < 4; q++) {
            p0[q] = (bf16)bRf[0][q]; p0[q + 4] = (bf16)bRf[1][q];
            p1[q] = (bf16)bRf[2][q]; p1[q + 4] = (bf16)bRf[3][q];
        }
        *(bf16x8*)&lB[0][srow][schunk * 16]     = p0;
        *(bf16x8*)&lB[0][srow][schunk * 16 + 8] = p1;
    }
    __syncthreads();

    int cur = 0;
    for (int ks = 0; ks < nk; ks++) {
        if (ks + 1 < nk) {
            aR0 = *(const u32x4*)(agp + (ks + 1) * 64);
            aR1 = *(const u32x4*)(agp + (ks + 1) * 64 + 8);
#pragma unroll
            for (int q = 0; q < 4; q++) bRf[q] = *(const fx4*)(bgp + (ks + 1) * 64 + q * 4);
        }
        int rA = lane & 15;
        int kc = (lane >> 4) * 8;
#pragma unroll
        for (int kk = 0; kk < 2; kk++) {
            bf16x8 bfr = *(bf16x8*)&lB[cur][wid * 16 + rA][kk * 32 + kc];
#pragma unroll
            for (int i = 0; i < 4; i++) {
                bf16x8 af = *(bf16x8*)&lA[cur][i * 16 + rA][kk * 32 + kc];
                acc[i] = MFMA16x16x32(af, bfr, acc[i]);
            }
        }
        if (ks + 1 < nk) {
            int nxt = cur ^ 1;
            *(u32x4*)&lA[nxt][srow][schunk * 16]     = aR0;
            *(u32x4*)&lA[nxt][srow][schunk * 16 + 8] = aR1;
            bf16x8 p0, p1;
#pragma unroll
            for (int q = 0; q < 4; q++) {
                p0[q] = (bf16)bRf[0][q]; p0[q + 4] = (bf16)bRf[1][q];
                p1[q] = (bf16)bRf[2][q]; p1[q + 4] = (bf16)bRf[3][q];
            }
            *(bf16x8*)&lB[nxt][srow][schunk * 16]     = p0;
            *(bf16x8*)&lB[nxt][srow][schunk * 16 + 8] = p1;
        }
        __syncthreads();
        cur ^= 1;
    }

    int n = n0 + wid * 16 + (lane & 15);
#pragma unroll
    for (int i = 0; i < 4; i++) {
#pragma unroll
        for (int r = 0; r < 4; r++) {
            int m = i * 16 + (lane >> 4) * 4 + r;
            float v = acc[i][r];
            if (finalOut) op[(size_t)m * N + n] = v + bias[n];
            else          op[(size_t)(sk * 64 + m) * N + n] = v;
        }
    }
}

// ===========================================================================
// k_attn v7: 256x128 tile, BK=32, 8 waves (4m x 2n, 64x64 each),
// TRIPLE-buffered LDS (3 x 24KB = 72KB) -> 2 blocks/CU (TLP fills the
// read-burst/MFMA-burst serialization that capped v3/v5/v6 at ~38% util).
// __launch_bounds__(512,4) caps VGPR<=128 so 16 waves/CU actually fit.
// Stage kt+2 via global_load_lds (3 calls/wave), counted vmcnt(3) -> ~2
// tiles of slack; ONE barrier per K-tile. 64B LDS rows with chunk-XOR
// swizzle c ^= (row>>1)&3 (both sides): in-order 8-lane groups of a
// b128 hit 8 distinct bank-quads -> conflict-free.
// Fused epilogue: relu(hA+hB+b1)*W2 -> scores_part[nbp*2+wn][m].
// ===========================================================================
__global__ __launch_bounds__(512, 4) void k_attn(
    const bf16* __restrict__ annb, const bf16* __restrict__ Bw,
    const float* __restrict__ p_hB, const float* __restrict__ b1v,
    const float* __restrict__ W2, float* __restrict__ scores_part)
{
    extern __shared__ char smem[];               // 3 x (A 16KB | B 8KB)

    int bid = blockIdx.x;
    int wgid = (bid & 7) * 128 + (bid >> 3);     // XCD-contiguous (1024%8==0)
    int mb = wgid >> 3, nbp = wgid & 7;          // 128 m-panels x 8 n-panels

    int t = threadIdx.x, lane = t & 63, wid = t >> 6;
    int wm = wid >> 1, wn = wid & 1;
    int r = lane & 15, q = lane >> 4;

    // ---- staging source addresses (per-lane, inverse-swizzled chunk) ----
    int la4 = lane >> 2, lc = lane & 3;
    int rowl0 = wid * 32 + la4;                  // A call 0 rows
    int rowl1 = rowl0 + 16;                      // A call 1 rows
    int rowlb = wid * 16 + la4;                  // B rows
    const bf16* aS0 = annb + (size_t)(mb * 256 + rowl0) * 1024
                    + ((lc ^ ((rowl0 >> 1) & 3)) << 3);
    const bf16* aS1 = annb + (size_t)(mb * 256 + rowl1) * 1024
                    + ((lc ^ ((rowl1 >> 1) & 3)) << 3);
    const bf16* bS0 = Bw + (size_t)(nbp * 128 + rowlb) * 1024
                    + ((lc ^ ((rowlb >> 1) & 3)) << 3);

#define STAGE(kt, bufb) do {                                                   \
        char* d_ = smem + (bufb);                                              \
        gload_lds16(aS0 + (size_t)(kt) * 32, (bf16*)(d_ + wid * 2048));        \
        gload_lds16(aS1 + (size_t)(kt) * 32, (bf16*)(d_ + wid * 2048 + 1024)); \
        gload_lds16(bS0 + (size_t)(kt) * 32, (bf16*)(d_ + 16384 + wid * 1024));\
    } while (0)

#define VMW(n) asm volatile("s_waitcnt vmcnt(" #n ")" ::: "memory")

    // ---- fragment read byte offsets (swizzled) ----
    int rAo[4], rBo[4];
#pragma unroll
    for (int i = 0; i < 4; i++) {
        int row = wm * 64 + i * 16 + r;
        rAo[i] = row * 64 + ((q ^ ((row >> 1) & 3)) << 4);
    }
#pragma unroll
    for (int j = 0; j < 4; j++) {
        int row = wn * 64 + j * 16 + r;
        rBo[j] = 16384 + row * 64 + ((q ^ ((row >> 1) & 3)) << 4);
    }

    f32x4 acc[4][4];
#pragma unroll
    for (int i = 0; i < 4; i++)
#pragma unroll
        for (int j = 0; j < 4; j++) acc[i][j] = (f32x4)0.0f;

    // prologue: tiles 0,1 staged; wait tile0 (3 of tile1 remain)
    STAGE(0, 0);
    STAGE(1, 24576);
    VMW(3);
    __builtin_amdgcn_s_barrier();

    int buf0 = 0, buf1 = 24576, buf2 = 49152;    // rotating buffer offsets
#pragma unroll 1
    for (int kt = 0; kt < 32; kt++) {
        if (kt <= 29) STAGE(kt + 2, buf2);

        const char* base = smem + buf0;
        bf16x8 aq[4], bq[4];
#pragma unroll
        for (int i = 0; i < 4; i++) aq[i] = *(const bf16x8*)(base + rAo[i]);
#pragma unroll
        for (int j = 0; j < 4; j++) bq[j] = *(const bf16x8*)(base + rBo[j]);

        __builtin_amdgcn_s_setprio(1);
#pragma unroll
        for (int i = 0; i < 4; i++)
#pragma unroll
            for (int j = 0; j < 4; j++)
                acc[i][j] = MFMA16x16x32(aq[i], bq[j], acc[i][j]);
        __builtin_amdgcn_s_setprio(0);

        if (kt <= 29)      { VMW(3); }
        else if (kt == 30) { VMW(0); }
        if (kt < 31) __builtin_amdgcn_s_barrier();

        int tmp = buf0; buf0 = buf1; buf1 = buf2; buf2 = tmp;
    }
#undef STAGE

    // fused epilogue: relu(hA + hB + b1) * W2, reduce over this block's 128 n
    int m0 = mb * 256;
    int b = mb >> 1;                             // single batch per block
    float hb[4], w2v[4];
#pragma unroll
    for (int j = 0; j < 4; j++) {
        int n = nbp * 128 + wn * 64 + j * 16 + r;
        float h = p_hB[b * Hh + n] + p_hB[65536 + b * Hh + n]
                + p_hB[131072 + b * Hh + n] + p_hB[196608 + b * Hh + n];
        hb[j]  = h + b1v[n];
        w2v[j] = W2[n];
    }
    float red[16];
#pragma unroll
    for (int i = 0; i < 4; i++)
#pragma unroll
        for (int rr = 0; rr < 4; rr++) {
            float s = 0.f;
#pragma unroll
            for (int j = 0; j < 4; j++) {
                float v = acc[i][j][rr] + hb[j];
                v = fmaxf(v, 0.f);
                s += v * w2v[j];
            }
            red[i * 4 + rr] = s;
        }
#pragma unroll
    for (int mask = 1; mask <= 8; mask <<= 1)
#pragma unroll
        for (int p = 0; p < 16; p++)
            red[p] += __shfl_xor(red[p], mask, 64);

    if (r == 0) {
        float* sp = scores_part + (size_t)(nbp * 2 + wn) * Mtot;
#pragma unroll
        for (int i = 0; i < 4; i++) {
            int m = m0 + wm * 64 + i * 16 + q * 4;
#pragma unroll
            for (int rr = 0; rr < 4; rr++)
                sp[m + rr] = red[i * 4 + rr];
        }
    }
}

// ===========================================================================
// k_softmax: per b (64 blocks x 512 thr): sum 16 partials, softmax over s.
// ===========================================================================
__global__ void k_softmax(const float* __restrict__ scores_part, float* __restrict__ aw)
{
    int b = blockIdx.x, s = threadIdx.x;
    int lane = s & 63, wid = s >> 6;
    float v = 0.f;
#pragma unroll
    for (int p = 0; p < 16; p++) v += scores_part[(size_t)p * Mtot + b * Ss + s];

    __shared__ float redm[8], redsum[8];
    float m = v;
#pragma unroll
    for (int mask = 32; mask; mask >>= 1) m = fmaxf(m, __shfl_xor(m, mask, 64));
    if (lane == 0) redm[wid] = m;
    __syncthreads();
    float bm = redm[0];
#pragma unroll
    for (int w = 1; w < 8; w++) bm = fmaxf(bm, redm[w]);

    float e = expf(v - bm);
    float ss = e;
#pragma unroll
    for (int mask = 32; mask; mask >>= 1) ss += __shfl_xor(ss, mask, 64);
    if (lane == 0) redsum[wid] = ss;
    __syncthreads();
    float tot = 0.f;
#pragma unroll
    for (int w = 0; w < 8; w++) tot += redsum[w];

    aw[b * Ss + s] = e / tot;
}

// ===========================================================================
// k_context: ctx_part[sc][b][h] = sum_{s in 64-chunk} aw[b,s]*annb[b,s,h]
// ===========================================================================
__global__ void k_context(const bf16* __restrict__ annb, const float* __restrict__ aw,
                          float* __restrict__ ctx_part)
{
    __shared__ float law[64];
    int bid = blockIdx.x;
    int b = bid >> 3, sc = bid & 7;
    int t = threadIdx.x;
    if (t < 64) law[t] = aw[b * Ss + sc * 64 + t];
    __syncthreads();
    int h0 = t * 4;
    const bf16* ap = annb + (size_t)(b * Ss + sc * 64) * Hh + h0;
    float a0 = 0, a1 = 0, a2 = 0, a3 = 0;
#pragma unroll 4
    for (int s2 = 0; s2 < 64; s2++) {
        float w = law[s2];
        u32x2 v = *(const u32x2*)(ap + (size_t)s2 * Hh);
        a0 += w * bf2f((unsigned short)(v[0] & 0xffff));
        a1 += w * bf2f((unsigned short)(v[0] >> 16));
        a2 += w * bf2f((unsigned short)(v[1] & 0xffff));
        a3 += w * bf2f((unsigned short)(v[1] >> 16));
    }
    fx4 o; o[0] = a0; o[1] = a1; o[2] = a2; o[3] = a3;
    *(fx4*)(ctx_part + sc * 65536 + b * Hh + h0) = o;
}

// ===========================================================================
// k_xc: xc_b[:, 0:H] = bf16(sum of 8 ctx partials)
// ===========================================================================
__global__ void k_xc(const float* __restrict__ ctx_part, bf16* __restrict__ xc_b)
{
    int idx = blockIdx.x * 256 + threadIdx.x;          // 65536
    float c = 0.f;
#pragma unroll
    for (int p = 0; p < 8; p++) c += ctx_part[p * 65536 + idx];
    int b = idx >> 10, h = idx & 1023;
    xc_b[b * 2048 + h] = (bf16)c;
}

// ===========================================================================
// k_gru: gates + h_new (reads 4-way split-K partials)
// ===========================================================================
__global__ void k_gru(const float* __restrict__ p_iz, const float* __restrict__ p_ir,
                      const float* __restrict__ p_in, const float* __restrict__ p_hz,
                      const float* __restrict__ p_hn,
                      const float* __restrict__ b_iz, const float* __restrict__ b_ir,
                      const float* __restrict__ b_in, const float* __restrict__ b_hz,
                      const float* __restrict__ b_hn,
                      const float* __restrict__ h_prev,
                      float* __restrict__ out_h, bf16* __restrict__ h_new_b)
{
    int idx = blockIdx.x * 256 + threadIdx.x;          // 65536
    int o = idx & 1023;
    float iz = p_iz[idx] + p_iz[65536 + idx] + p_iz[131072 + idx] + p_iz[196608 + idx];
    float ir = p_ir[idx] + p_ir[65536 + idx] + p_ir[131072 + idx] + p_ir[196608 + idx];
    float in_ = p_in[idx] + p_in[65536 + idx] + p_in[131072 + idx] + p_in[196608 + idx];
    float hz = p_hz[idx] + p_hz[65536 + idx] + p_hz[131072 + idx] + p_hz[196608 + idx];
    float hn = p_hn[idx] + p_hn[65536 + idx] + p_hn[131072 + idx] + p_hn[196608 + idx];
    hz += b_hz[o];
    hn += b_hn[o];
    float z = 1.f / (1.f + expf(-(iz + b_iz[o] + hz)));
    float r = 1.f / (1.f + expf(-(ir + b_ir[o] + hz)));
    float g = tanhf(in_ + b_in[o] + r * hn);
    float hp = h_prev[idx];
    float hnew = (1.f - z) * g + z * hp;
    out_h[idx] = hnew;
    h_new_b[idx] = (bf16)hnew;
}

// ===========================================================================
extern "C" void kernel_launch(void* const* d_in, const int* in_sizes, int n_in,
                              void* d_out, int out_size, void* d_ws, size_t ws_size,
                              hipStream_t stream)
{
    const int*   x        = (const int*)d_in[0];
    const float* h_prev   = (const float*)d_in[1];
    const float* ann      = (const float*)d_in[2];
    const float* emb      = (const float*)d_in[3];
    const float* attn_W1  = (const float*)d_in[4];
    const float* attn_b1  = (const float*)d_in[5];
    const float* attn_W2  = (const float*)d_in[6];
    const float* W_ir     = (const float*)d_in[8];
    const float* b_ir     = (const float*)d_in[9];
    const float* W_iz     = (const float*)d_in[10];
    const float* b_iz     = (const float*)d_in[11];
    const float* W_in     = (const float*)d_in[12];
    const float* b_in     = (const float*)d_in[13];
    const float* W_hz     = (const float*)d_in[14];
    const float* b_hz     = (const float*)d_in[15];
    const float* W_hn     = (const float*)d_in[16];
    const float* b_hn     = (const float*)d_in[17];
    const float* W_out    = (const float*)d_in[18];
    const float* b_out    = (const float*)d_in[19];

    float* out = (float*)d_out;
    char*  ws  = (char*)d_ws;

    bf16*  h_new_b  = (bf16*)(ws + WS_HNEW_B);
    bf16*  xc_b     = (bf16*)(ws + WS_XC_B);
    bf16*  W1a_b    = (bf16*)(ws + WS_W1A_B);
    float* p_hB     = (float*)(ws + WS_P_HB);
    float* p_hz     = (float*)(ws + WS_P_HZ);
    float* p_hn     = (float*)(ws + WS_P_HN);
    float* p_iz     = (float*)(ws + WS_P_IZ);
    float* p_ir     = (float*)(ws + WS_P_IR);
    float* p_in     = (float*)(ws + WS_P_IN);
    float* scores_p = (float*)(ws + WS_SCORES);
    float* ctx_part = (float*)(ws + WS_CTX);
    bf16*  annb     = (bf16*)(ws + WS_ANNB);

    // allow dynamic LDS for k_attn (host-side attribute, capture-safe)
    (void)hipFuncSetAttribute(reinterpret_cast<const void*>(k_attn),
                              hipFuncAttributeMaxDynamicSharedMemorySize, 131072);

    // 1) merged pre-work: convann + prep + hB/hz/hn GEMMs (overlapped)
    k_pre<<<3328, 256, 0, stream>>>(x, h_prev, emb, attn_W1, W_hz, W_hn, ann,
                                    xc_b, W1a_b, annb, p_hB, p_hz, p_hn);

    // 2) fused attention GEMM -> 16 score partials
    k_attn<<<1024, 512, 73728, stream>>>(annb, W1a_b, p_hB, attn_b1, attn_W2,
                                         scores_p);

    // 3) softmax -> attention weights (final output region)
    k_softmax<<<64, 512, 0, stream>>>(scores_p, out + OUT_AW);

    // 4) context = sum_s aw * annb  (8 s-chunks)
    k_context<<<512, 256, 0, stream>>>(annb, out + OUT_AW, ctx_part);

    // 5) xc = [context, embed] in bf16
    k_xc<<<256, 256, 0, stream>>>(ctx_part, xc_b);

    // 6) gate GEMMs (xc @ {W_iz, W_ir, W_in}^T), K=2048, split-K=4
    {
        dim3 g(16, 4, 3);
        k_sgemm<<<g, 256, 0, stream>>>(xc_b, 2048, 512,
                                       W_iz, W_ir, W_in, 2048, 2048, 2048,
                                       p_iz, p_ir, p_in, nullptr, 1024, 0);
    }

    // 7) GRU elementwise -> h_new (f32 out + bf16 ws)
    k_gru<<<256, 256, 0, stream>>>(p_iz, p_ir, p_in, p_hz, p_hn,
                                   b_iz, b_ir, b_in, b_hz, b_hn,
                                   h_prev, out + OUT_HNEW, h_new_b);

    // 8) output logits = h_new @ W_out^T + b_out
    {
        dim3 g(500, 1, 1);
        k_sgemm<<<g, 256, 0, stream>>>(h_new_b, 1024, 1024,
                                       W_out, W_out, W_out, 1024, 1024, 1024,
                                       out + OUT_LOGITS, nullptr, nullptr,
                                       b_out, 32000, 1);
    }
}